// Round 10
// baseline (136.115 us; speedup 1.0000x reference)
//
#include <hip/hip_runtime.h>

#define HW_ELEMS (512 * 512)             // elements per (n,c) channel
#define HW4      (HW_ELEMS / 4)          // 65536 fx4 per channel
#define NC 192
#define THREADS 256
#define BPC 4                            // blocks per channel
#define SLICE4 (HW4 / BPC)               // 16384 fx4 per slice (256 KB)
#define NBLK (NC * BPC)                  // 768 blocks = 3/CU co-resident
#define EPS 1e-8f
#define B1 16                            // phase-1 batch (loads only)
#define B2 8                             // phase-2 batch (pipelined ld/st)

typedef float fx4 __attribute__((ext_vector_type(4)));

// Fused single-read instance norm. R8 post-mortem: phase 2's ~1.9 TB/s came
// from vmcnt load/store coupling (waiting on batch-k loads also waits on
// batch-(k-1) nt-stores). Fix: software pipeline — issue batch k+1 loads
// BEFORE batch k stores, giving stores a full iteration to drain.
__global__ __launch_bounds__(THREADS, 3) void instnorm_coop(
    const float* __restrict__ in, float* __restrict__ out,
    float* __restrict__ psum, float* __restrict__ psq,
    unsigned* __restrict__ sem)
{
    const int s = blockIdx.x;
    const int c = s >> 2;                 // channel  (BPC=4)
    const int b = s & (BPC - 1);          // slice within channel
    const size_t base = (size_t)c * HW4 + (size_t)b * SLICE4;
    const fx4* p = reinterpret_cast<const fx4*>(in) + base;
    fx4* q = reinterpret_cast<fx4*>(out) + base;
    const int t = threadIdx.x;

    // ---- pass 1: slice stats (loads + FMA only; no store coupling) ----
    float sum = 0.f, sq = 0.f;
    for (int k = 0; k < SLICE4 / THREADS / B1; ++k) {     // 4 outer iters
        fx4 v[B1];
#pragma unroll
        for (int u = 0; u < B1; ++u)
            v[u] = p[t + (k * B1 + u) * THREADS];
#pragma unroll
        for (int u = 0; u < B1; ++u) {
            sum += (v[u].x + v[u].y) + (v[u].z + v[u].w);
            sq  += v[u].x * v[u].x + v[u].y * v[u].y
                 + v[u].z * v[u].z + v[u].w * v[u].w;
        }
    }
#pragma unroll
    for (int off = 32; off > 0; off >>= 1) {
        sum += __shfl_down(sum, off, 64);
        sq  += __shfl_down(sq,  off, 64);
    }
    __shared__ float s_red[8];
    if ((t & 63) == 0) { s_red[t >> 6] = sum; s_red[4 + (t >> 6)] = sq; }
    __syncthreads();

    // ---- t0: publish partial, sync channel (relaxed spin), combine ----
    __shared__ float s_mean, s_rstd;
    if (t == 0) {
        float S = s_red[0] + s_red[1] + s_red[2] + s_red[3];
        float Q = s_red[4] + s_red[5] + s_red[6] + s_red[7];
        __hip_atomic_store(&psum[s], S, __ATOMIC_RELAXED, __HIP_MEMORY_SCOPE_AGENT);
        __hip_atomic_store(&psq[s],  Q, __ATOMIC_RELAXED, __HIP_MEMORY_SCOPE_AGENT);
        __hip_atomic_fetch_add(&sem[c], 1u, __ATOMIC_RELEASE, __HIP_MEMORY_SCOPE_AGENT);
        while (__hip_atomic_load(&sem[c], __ATOMIC_RELAXED, __HIP_MEMORY_SCOPE_AGENT) < BPC)
            __builtin_amdgcn_s_sleep(1);
        float Sa = 0.f, Qa = 0.f;
#pragma unroll
        for (int i = 0; i < BPC; ++i) {
            Sa += __hip_atomic_load(&psum[c * BPC + i], __ATOMIC_RELAXED, __HIP_MEMORY_SCOPE_AGENT);
            Qa += __hip_atomic_load(&psq[c * BPC + i],  __ATOMIC_RELAXED, __HIP_MEMORY_SCOPE_AGENT);
        }
        const float n = (float)HW_ELEMS;
        float mean = Sa / n;
        float var  = (Qa - Sa * Sa / n) / (n - 1.0f);     // unbiased (ddof=1)
        if (var < 0.f) var = 0.f;
        s_mean = mean;
        s_rstd = 1.0f / (sqrtf(var) + EPS);
    }
    __syncthreads();
    const float mean = s_mean;
    const float rstd = s_rstd;

    // ---- pass 2: software-pipelined normalize ----
    // vmem issue order: ... L(k+1), [wait L(k) -> allows S(k-1)+L(k+1)
    // outstanding], S(k), ...  => stores get one full iteration to drain.
    constexpr int NB = SLICE4 / THREADS / B2;             // 8 batches
    fx4 cur[B2], nxt[B2];
#pragma unroll
    for (int u = 0; u < B2; ++u) cur[u] = p[t + u * THREADS];
#pragma unroll
    for (int k = 0; k < NB; ++k) {
        if (k + 1 < NB) {
#pragma unroll
            for (int u = 0; u < B2; ++u)
                nxt[u] = p[t + ((k + 1) * B2 + u) * THREADS];
        }
#pragma unroll
        for (int u = 0; u < B2; ++u) {
            fx4 r = (cur[u] - mean) * rstd;
            __builtin_nontemporal_store(r, q + t + (k * B2 + u) * THREADS);
        }
#pragma unroll
        for (int u = 0; u < B2; ++u) cur[u] = nxt[u];
    }
}

// ---------- fallback path (two-kernel, R3-proven) ----------
__global__ __launch_bounds__(256) void instnorm_partial(
    const float* __restrict__ in, float* __restrict__ psum, float* __restrict__ psq)
{
    const int c = blockIdx.x >> 2;
    const int b = blockIdx.x & (BPC - 1);
    const fx4* p = reinterpret_cast<const fx4*>(in)
                 + (size_t)c * HW4 + (size_t)b * SLICE4;
    const int t = threadIdx.x;
    float sum = 0.f, sq = 0.f;
    for (int k = 0; k < SLICE4 / 256 / B1; ++k) {
        fx4 v[B1];
#pragma unroll
        for (int u = 0; u < B1; ++u)
            v[u] = p[t + (k * B1 + u) * 256];
#pragma unroll
        for (int u = 0; u < B1; ++u) {
            sum += (v[u].x + v[u].y) + (v[u].z + v[u].w);
            sq  += v[u].x * v[u].x + v[u].y * v[u].y
                 + v[u].z * v[u].z + v[u].w * v[u].w;
        }
    }
#pragma unroll
    for (int off = 32; off > 0; off >>= 1) {
        sum += __shfl_down(sum, off, 64);
        sq  += __shfl_down(sq,  off, 64);
    }
    __shared__ float s_red[8];
    if ((t & 63) == 0) { s_red[t >> 6] = sum; s_red[4 + (t >> 6)] = sq; }
    __syncthreads();
    if (t == 0) {
        psum[blockIdx.x] = s_red[0] + s_red[1] + s_red[2] + s_red[3];
        psq[blockIdx.x]  = s_red[4] + s_red[5] + s_red[6] + s_red[7];
    }
}

__global__ __launch_bounds__(256) void instnorm_apply(
    const float* __restrict__ in, float* __restrict__ out,
    const float* __restrict__ psum, const float* __restrict__ psq)
{
    const int c = blockIdx.x >> 8;
    float S = 0.f, Q = 0.f;
#pragma unroll
    for (int i = 0; i < BPC; ++i) { S += psum[c * BPC + i]; Q += psq[c * BPC + i]; }
    const float n = (float)HW_ELEMS;
    float mean = S / n;
    float var  = (Q - S * S / n) / (n - 1.0f);
    if (var < 0.f) var = 0.f;
    float rstd = 1.0f / (sqrtf(var) + EPS);

    const size_t i4 = (size_t)blockIdx.x * 256 + threadIdx.x;
    fx4 v = reinterpret_cast<const fx4*>(in)[i4];
    fx4 r = (v - mean) * rstd;
    __builtin_nontemporal_store(r, reinterpret_cast<fx4*>(out) + i4);
}

extern "C" void kernel_launch(void* const* d_in, const int* in_sizes, int n_in,
                              void* d_out, int out_size, void* d_ws, size_t ws_size,
                              hipStream_t stream) {
    const float* in = (const float*)d_in[0];
    float* out = (float*)d_out;
    // ws layout: psum[NBLK] | psq[NBLK] | sem[NC]
    float*    psum = (float*)d_ws;
    float*    psq  = psum + NBLK;
    unsigned* sem  = (unsigned*)(psq + NBLK);

    hipMemsetAsync(sem, 0, NC * sizeof(unsigned), stream);

    void* args[] = { (void*)&in, (void*)&out, (void*)&psum, (void*)&psq, (void*)&sem };
    hipError_t rc = hipLaunchCooperativeKernel((const void*)instnorm_coop,
                                               dim3(NBLK), dim3(THREADS),
                                               args, 0, stream);
    if (rc != hipSuccess) {
        instnorm_partial<<<NBLK, 256, 0, stream>>>(in, psum, psq);
        const size_t total4 = (size_t)NC * HW4;
        instnorm_apply<<<(int)(total4 / 256), 256, 0, stream>>>(in, out, psum, psq);
    }
}